// Round 3
// baseline (285.546 us; speedup 1.0000x reference)
//
#include <hip/hip_runtime.h>
#include <hip/hip_bf16.h>

// TransformerBlock: B=8,S=196,D=768,H=12,HD=64,E=8,FF=3072. T = B*S = 1568 tokens.
//
// Exact simplifications:
//  - attention: k,v broadcast across heads -> logits constant over softmax axis
//    -> softmax uniform -> attn_out = tile(v). Wq/bq/Wk/bk/RoPE are dead code.
//  - MoE top-1 = argmax of gating logits (softmax monotone).
//
// R4 structure:
//  - k_front: ONE WAVE PER TOKEN (1568 blocks x 64 threads). R3 post-mortem:
//    old 196-block k_front was 57us at 0% MFMA / 6.7% VALU / 7.7% occupancy --
//    pure latency bound (<1 wave/SIMD). Now: LN1 -> vproj (lane = out col,
//    h1 broadcast via 3KB LDS, Wv coalesced rows from L2) -> LN2/gate/out-init
//    all in-wave, no LDS param staging (Wg/g2/b2 read coalesced from L2 in a
//    c = 4*lane + 256*i layout). L2 floor ~9us vs 57us measured before.
//  - MoE GEMMs unchanged from R3: BM=128,BN=64,BK=64, depth-2 reg prefetch,
//    raw s_barrier (no vmcnt drain), clamped A-token indices.
//  - GEMM2 split-K x4 atomicAdds onto out pre-initialized with x2 + b2[expert].

typedef unsigned short u16;
typedef short bf16x8_t __attribute__((ext_vector_type(8)));
typedef unsigned short u16x4_t __attribute__((ext_vector_type(4)));
typedef float f32x4_t  __attribute__((ext_vector_type(4)));

#define T_TOK 1568
#define DM 768
#define HD 64
#define FF 3072
#define NE 8

// workspace layout (16B-aligned offsets; ~12.1 MB total)
#define OFF_CNT   0
#define OFF_BUCK  256
#define OFF_H2    (OFF_BUCK + NE*T_TOK*4)
#define OFF_HMID  (OFF_H2 + T_TOK*DM*2)

__device__ __forceinline__ u16 f2bf(float f) {  // RNE via HW cvt
    return __builtin_bit_cast(u16, __float2bfloat16(f));
}
__device__ __forceinline__ float gelu_f(float x) {
    return 0.5f * x * (1.0f + erff(x * 0.70710678118654752440f));
}

#define SFENCE() __builtin_amdgcn_sched_barrier(0)
#define RAW_BAR() __builtin_amdgcn_s_barrier()

// ---------------- K1: fused per-token front end (1 wave / token) ----------------
// Lane owns cols c(i,m) = 4*lane + 256*i + m (i<3, m<4): all param/x/out
// accesses are coalesced f32x4. vproj: lane j computes v[j] (full 768-dot,
// h1 broadcast from LDS, Wv rows coalesced from L2).
__global__ __launch_bounds__(64) void k_front(
        const float* __restrict__ x,
        const float* __restrict__ g1, const float* __restrict__ b1,
        const float* __restrict__ Wv, const float* __restrict__ bv,
        const float* __restrict__ g2, const float* __restrict__ b2g,
        const float* __restrict__ Wg, const float* __restrict__ bg,
        const float* __restrict__ b2moe,
        u16* __restrict__ h2, float* __restrict__ out,
        int* __restrict__ cnt, int* __restrict__ buck) {
    __shared__ __align__(16) float h1s[DM];   // 3 KB
    __shared__ __align__(16) float vsh[HD];   // 256 B
    int t = blockIdx.x;
    int lane = threadIdx.x;                   // 0..63, single wave

    const float* xp = x + (size_t)t * DM;
    // ---- LN1 ----
    f32x4_t xv[3];
    float s = 0.0f;
#pragma unroll
    for (int i = 0; i < 3; i++) {
        xv[i] = *(const f32x4_t*)&xp[4 * lane + 256 * i];
        s += xv[i][0] + xv[i][1] + xv[i][2] + xv[i][3];
    }
#pragma unroll
    for (int m = 1; m < 64; m <<= 1) s += __shfl_xor(s, m);
    float mu = s * (1.0f / DM);
    float vs = 0.0f;
#pragma unroll
    for (int i = 0; i < 3; i++)
#pragma unroll
        for (int m = 0; m < 4; m++) { float d = xv[i][m] - mu; vs += d * d; }
#pragma unroll
    for (int m = 1; m < 64; m <<= 1) vs += __shfl_xor(vs, m);
    float rs = rsqrtf(vs * (1.0f / DM) + 1e-5f);
#pragma unroll
    for (int i = 0; i < 3; i++) {
        int c = 4 * lane + 256 * i;
        f32x4_t gg = *(const f32x4_t*)&g1[c];
        f32x4_t bb = *(const f32x4_t*)&b1[c];
        f32x4_t h;
#pragma unroll
        for (int m = 0; m < 4; m++) h[m] = (xv[i][m] - mu) * rs * gg[m] + bb[m];
        *(f32x4_t*)&h1s[c] = h;
    }
    __syncthreads();

    // ---- vproj: v[lane] = sum_k h1s[k] * Wv[k][lane] ----
    {
        float a0 = 0.f, a1 = 0.f, a2 = 0.f, a3 = 0.f;
        const float* wp = Wv + lane;
#pragma unroll 2
        for (int k = 0; k < DM; k += 8) {
            f32x4_t h0 = *(const f32x4_t*)&h1s[k];
            f32x4_t h4 = *(const f32x4_t*)&h1s[k + 4];
            a0 += h0[0] * wp[(size_t)(k + 0) * HD] + h4[0] * wp[(size_t)(k + 4) * HD];
            a1 += h0[1] * wp[(size_t)(k + 1) * HD] + h4[1] * wp[(size_t)(k + 5) * HD];
            a2 += h0[2] * wp[(size_t)(k + 2) * HD] + h4[2] * wp[(size_t)(k + 6) * HD];
            a3 += h0[3] * wp[(size_t)(k + 3) * HD] + h4[3] * wp[(size_t)(k + 7) * HD];
        }
        vsh[lane] = a0 + a1 + a2 + a3 + bv[lane];
    }
    __syncthreads();

    // ---- x2 = x + tile(v); LN2; gate; out init ----
    // col c -> v[c & 63]; c = 4*lane + 256*i + m -> v[4*(lane&15) + m]
    f32x4_t vv = *(const f32x4_t*)&vsh[4 * (lane & 15)];
    float s2 = 0.0f;
#pragma unroll
    for (int i = 0; i < 3; i++)
#pragma unroll
        for (int m = 0; m < 4; m++) { xv[i][m] += vv[m]; s2 += xv[i][m]; }
#pragma unroll
    for (int m = 1; m < 64; m <<= 1) s2 += __shfl_xor(s2, m);
    float mu2 = s2 * (1.0f / DM);
    float vs2 = 0.0f;
#pragma unroll
    for (int i = 0; i < 3; i++)
#pragma unroll
        for (int m = 0; m < 4; m++) { float d = xv[i][m] - mu2; vs2 += d * d; }
#pragma unroll
    for (int m = 1; m < 64; m <<= 1) vs2 += __shfl_xor(vs2, m);
    float rs2 = rsqrtf(vs2 * (1.0f / DM) + 1e-5f);

    float le[NE];
#pragma unroll
    for (int e = 0; e < NE; e++) le[e] = 0.0f;
    u16* h2p = h2 + (size_t)t * DM;
#pragma unroll
    for (int i = 0; i < 3; i++) {
        int c = 4 * lane + 256 * i;
        f32x4_t gg = *(const f32x4_t*)&g2[c];
        f32x4_t bb = *(const f32x4_t*)&b2g[c];
        float h[4];
        u16x4_t hb;
#pragma unroll
        for (int m = 0; m < 4; m++) {
            h[m] = (xv[i][m] - mu2) * rs2 * gg[m] + bb[m];
            hb[m] = f2bf(h[m]);
        }
        *(u16x4_t*)&h2p[c] = hb;   // 8B coalesced
        // gate: rows c..c+3 of Wg[768][8] are 128B contiguous per lane
#pragma unroll
        for (int m = 0; m < 4; m++) {
            f32x4_t w0 = *(const f32x4_t*)&Wg[(size_t)(c + m) * NE];
            f32x4_t w1 = *(const f32x4_t*)&Wg[(size_t)(c + m) * NE + 4];
            le[0] += h[m] * w0[0]; le[1] += h[m] * w0[1];
            le[2] += h[m] * w0[2]; le[3] += h[m] * w0[3];
            le[4] += h[m] * w1[0]; le[5] += h[m] * w1[1];
            le[6] += h[m] * w1[2]; le[7] += h[m] * w1[3];
        }
    }
#pragma unroll
    for (int e = 0; e < NE; e++) {
#pragma unroll
        for (int m = 1; m < 64; m <<= 1) le[e] += __shfl_xor(le[e], m);
    }
    // all lanes hold bitwise-identical le[] (butterfly) -> uniform argmax
    float best = le[0] + bg[0]; int be = 0;
#pragma unroll
    for (int e = 1; e < NE; e++) {
        float q = le[e] + bg[e];
        if (q > best) { best = q; be = e; }   // strict > == first-max (jnp.argmax)
    }
    if (lane == 0) {
        int pos = atomicAdd(&cnt[be], 1);
        buck[be * T_TOK + pos] = t;
    }
    // out init: x2 + b2[be]  (gemm2 atomicAdds the MoE matmul on top)
    float* op = out + (size_t)t * DM;
    const float* bp = b2moe + (size_t)be * DM;
#pragma unroll
    for (int i = 0; i < 3; i++) {
        int c = 4 * lane + 256 * i;
        f32x4_t bbv = *(const f32x4_t*)&bp[c];
        f32x4_t o;
#pragma unroll
        for (int m = 0; m < 4; m++) o[m] = xv[i][m] + bbv[m];
        *(f32x4_t*)&op[c] = o;
    }
}

// ---------------- K2: grouped GEMM1 + gelu: hmid = gelu(h2 @ W1[e] + b1[e]) ----------------
// BM=128, BN=64, BK=64; 4 waves, wave -> 32-row strip x 64 cols.
// Depth-2 register prefetch + raw barriers (no vmcnt drain).
__global__ __launch_bounds__(256, 3) void k_moe_gemm1(
        const u16* __restrict__ h2, const float* __restrict__ W1,
        const float* __restrict__ b1, const int* __restrict__ cnt,
        const int* __restrict__ buck, u16* __restrict__ hmid) {
    int nt = blockIdx.x, e = blockIdx.y, mt = blockIdx.z;
    int cnte = cnt[e];
    int m0 = mt * 128;
    if (m0 >= cnte) return;
    int n0 = nt * 64;
    const float* W1e = W1 + (size_t)e * DM * FF;
    __shared__ __align__(16) u16 As[128 * 72];   // 18 KB
    __shared__ __align__(16) u16 Bs[64 * 72];    // 9 KB, [n][k]
    int tid = threadIdx.x, lane = tid & 63, wid = tid >> 6;

    // A staging: row = tid>>3 (+32j), col-chunk = tid&7. Clamped (unconditional).
    int arow = tid >> 3, ac = tid & 7;
    int atok[4];
#pragma unroll
    for (int j = 0; j < 4; j++) {
        int i = m0 + arow + 32 * j;
        if (i >= cnte) i = cnte - 1;           // garbage rows, never stored
        atok[j] = buck[e * T_TOK + i];
    }
    int bn = tid & 63, bkg = tid >> 6;

    f32x4_t acc[2][4];
#pragma unroll
    for (int mi = 0; mi < 2; mi++)
#pragma unroll
        for (int ni = 0; ni < 4; ni++) acc[mi][ni] = (f32x4_t){0.f, 0.f, 0.f, 0.f};

    bf16x8_t aP[4], aQ[4];
    float bP[16], bQ[16];

#define G_LOAD(SA, SB, KT) { \
    int k0_ = (KT) * 64; \
    _Pragma("unroll") \
    for (int j = 0; j < 4; j++) \
        SA[j] = *(const bf16x8_t*)&h2[(size_t)atok[j] * DM + k0_ + ac * 8]; \
    const float* bp_ = W1e + (size_t)(k0_ + bkg * 16) * FF + n0 + bn; \
    _Pragma("unroll") \
    for (int kk = 0; kk < 16; kk++) SB[kk] = bp_[(size_t)kk * FF]; \
}
#define STORE_LDS(SA, SB) { \
    _Pragma("unroll") \
    for (int j = 0; j < 4; j++) \
        *(bf16x8_t*)&As[(arow + 32 * j) * 72 + ac * 8] = SA[j]; \
    bf16x8_t p0_, p1_; \
    _Pragma("unroll") \
    for (int kk = 0; kk < 8; kk++) { \
        p0_[kk] = (short)f2bf(SB[kk]); \
        p1_[kk] = (short)f2bf(SB[kk + 8]); \
    } \
    *(bf16x8_t*)&Bs[bn * 72 + bkg * 16] = p0_; \
    *(bf16x8_t*)&Bs[bn * 72 + bkg * 16 + 8] = p1_; \
}
#define MFMA_TILE() { \
    int lr_ = lane & 15, q_ = lane >> 4; \
    _Pragma("unroll") \
    for (int s = 0; s < 2; s++) { \
        bf16x8_t af[2], bfr[4]; \
        _Pragma("unroll") \
        for (int mi = 0; mi < 2; mi++) \
            af[mi] = *(const bf16x8_t*)&As[(wid * 32 + mi * 16 + lr_) * 72 + s * 32 + q_ * 8]; \
        _Pragma("unroll") \
        for (int ni = 0; ni < 4; ni++) \
            bfr[ni] = *(const bf16x8_t*)&Bs[(ni * 16 + lr_) * 72 + s * 32 + q_ * 8]; \
        _Pragma("unroll") \
        for (int mi = 0; mi < 2; mi++) \
            _Pragma("unroll") \
            for (int ni = 0; ni < 4; ni++) \
                acc[mi][ni] = __builtin_amdgcn_mfma_f32_16x16x32_bf16( \
                    af[mi], bfr[ni], acc[mi][ni], 0, 0, 0); \
    } \
}
// one k-tile phase: raw barriers; own-wave lgkmcnt(0) after stores; prefetch
// set stays in flight across barriers (compiler emits counted vmcnt for the
// reg->LDS dependency only).
#define PHASE(SA, SB, PKT) { \
    SFENCE(); RAW_BAR(); SFENCE(); \
    STORE_LDS(SA, SB) \
    asm volatile("s_waitcnt lgkmcnt(0)" ::: "memory"); \
    SFENCE(); RAW_BAR(); SFENCE(); \
    if ((PKT) < 12) G_LOAD(SA, SB, PKT) \
    MFMA_TILE() \
}

    G_LOAD(aP, bP, 0)
    G_LOAD(aQ, bQ, 1)
    for (int kt = 0; kt < 12; kt += 2) {
        PHASE(aP, bP, kt + 2)
        PHASE(aQ, bQ, kt + 3)
    }
#undef G_LOAD
#undef STORE_LDS
#undef MFMA_TILE
#undef PHASE

    // epilogue: bias + gelu, scatter by token id
    int lr = lane & 15, q = lane >> 4;
    float bias[4];
#pragma unroll
    for (int ni = 0; ni < 4; ni++) bias[ni] = b1[(size_t)e * FF + n0 + ni * 16 + lr];
#pragma unroll
    for (int mi = 0; mi < 2; mi++) {
#pragma unroll
        for (int r = 0; r < 4; r++) {
            int i = m0 + wid * 32 + mi * 16 + q * 4 + r;
            if (i < cnte) {
                int t = buck[e * T_TOK + i];
                size_t base = (size_t)t * FF + n0;
#pragma unroll
                for (int ni = 0; ni < 4; ni++) {
                    float vv = acc[mi][ni][r] + bias[ni];
                    hmid[base + ni * 16 + lr] = f2bf(gelu_f(vv));
                }
            }
        }
    }
}

// ---------------- K3: grouped GEMM2 split-K x4: out += hmid @ W2[e] ----------------
// BM=128, BN=64, BK=64, K-chunk = FF/4 = 768. z = mt*4 + kc. Depth-2 prefetch,
// raw barriers.
__global__ __launch_bounds__(256, 3) void k_moe_gemm2(
        const u16* __restrict__ hmid, const float* __restrict__ W2,
        const int* __restrict__ cnt, const int* __restrict__ buck,
        float* __restrict__ out) {
    int nt = blockIdx.x, e = blockIdx.y, z = blockIdx.z;
    int kc = z & 3, mt = z >> 2;
    int cnte = cnt[e];
    int m0 = mt * 128;
    if (m0 >= cnte) return;
    int n0 = nt * 64;
    int kbase = kc * (FF / 4);
    const float* W2e = W2 + (size_t)e * FF * DM;
    __shared__ __align__(16) u16 As[128 * 72];
    __shared__ __align__(16) u16 Bs[64 * 72];
    int tid = threadIdx.x, lane = tid & 63, wid = tid >> 6;

    int arow = tid >> 3, ac = tid & 7;
    int atok[4];
#pragma unroll
    for (int j = 0; j < 4; j++) {
        int i = m0 + arow + 32 * j;
        if (i >= cnte) i = cnte - 1;           // garbage rows, never stored
        atok[j] = buck[e * T_TOK + i];
    }
    int bn = tid & 63, bkg = tid >> 6;

    f32x4_t acc[2][4];
#pragma unroll
    for (int mi = 0; mi < 2; mi++)
#pragma unroll
        for (int ni = 0; ni < 4; ni++) acc[mi][ni] = (f32x4_t){0.f, 0.f, 0.f, 0.f};

    bf16x8_t aP[4], aQ[4];
    float bP[16], bQ[16];

#define G_LOAD(SA, SB, KT) { \
    int k0_ = kbase + (KT) * 64; \
    _Pragma("unroll") \
    for (int j = 0; j < 4; j++) \
        SA[j] = *(const bf16x8_t*)&hmid[(size_t)atok[j] * FF + k0_ + ac * 8]; \
    const float* bp_ = W2e + (size_t)(k0_ + bkg * 16) * DM + n0 + bn; \
    _Pragma("unroll") \
    for (int kk = 0; kk < 16; kk++) SB[kk] = bp_[(size_t)kk * DM]; \
}
#define STORE_LDS(SA, SB) { \
    _Pragma("unroll") \
    for (int j = 0; j < 4; j++) \
        *(bf16x8_t*)&As[(arow + 32 * j) * 72 + ac * 8] = SA[j]; \
    bf16x8_t p0_, p1_; \
    _Pragma("unroll") \
    for (int kk = 0; kk < 8; kk++) { \
        p0_[kk] = (short)f2bf(SB[kk]); \
        p1_[kk] = (short)f2bf(SB[kk + 8]); \
    } \
    *(bf16x8_t*)&Bs[bn * 72 + bkg * 16] = p0_; \
    *(bf16x8_t*)&Bs[bn * 72 + bkg * 16 + 8] = p1_; \
}
#define MFMA_TILE() { \
    int lr_ = lane & 15, q_ = lane >> 4; \
    _Pragma("unroll") \
    for (int s = 0; s < 2; s++) { \
        bf16x8_t af[2], bfr[4]; \
        _Pragma("unroll") \
        for (int mi = 0; mi < 2; mi++) \
            af[mi] = *(const bf16x8_t*)&As[(wid * 32 + mi * 16 + lr_) * 72 + s * 32 + q_ * 8]; \
        _Pragma("unroll") \
        for (int ni = 0; ni < 4; ni++) \
            bfr[ni] = *(const bf16x8_t*)&Bs[(ni * 16 + lr_) * 72 + s * 32 + q_ * 8]; \
        _Pragma("unroll") \
        for (int mi = 0; mi < 2; mi++) \
            _Pragma("unroll") \
            for (int ni = 0; ni < 4; ni++) \
                acc[mi][ni] = __builtin_amdgcn_mfma_f32_16x16x32_bf16( \
                    af[mi], bfr[ni], acc[mi][ni], 0, 0, 0); \
    } \
}
#define PHASE(SA, SB, PKT) { \
    SFENCE(); RAW_BAR(); SFENCE(); \
    STORE_LDS(SA, SB) \
    asm volatile("s_waitcnt lgkmcnt(0)" ::: "memory"); \
    SFENCE(); RAW_BAR(); SFENCE(); \
    if ((PKT) < 12) G_LOAD(SA, SB, PKT) \
    MFMA_TILE() \
}

    G_LOAD(aP, bP, 0)
    G_LOAD(aQ, bQ, 1)
    for (int kt = 0; kt < 12; kt += 2) {
        PHASE(aP, bP, kt + 2)
        PHASE(aQ, bQ, kt + 3)
    }
#undef G_LOAD
#undef STORE_LDS
#undef MFMA_TILE
#undef PHASE

    // epilogue: atomicAdd partials into out (out pre-initialized with x2 + b2[e])
    int lr = lane & 15, q = lane >> 4;
#pragma unroll
    for (int mi = 0; mi < 2; mi++) {
#pragma unroll
        for (int r = 0; r < 4; r++) {
            int i = m0 + wid * 32 + mi * 16 + q * 4 + r;
            if (i < cnte) {
                int t = buck[e * T_TOK + i];
                size_t base = (size_t)t * DM + n0;
#pragma unroll
                for (int ni = 0; ni < 4; ni++)
                    atomicAdd(&out[base + ni * 16 + lr], acc[mi][ni][r]);
            }
        }
    }
}

extern "C" void kernel_launch(void* const* d_in, const int* in_sizes, int n_in,
                              void* d_out, int out_size, void* d_ws, size_t ws_size,
                              hipStream_t stream) {
    const float* x    = (const float*)d_in[0];
    const float* ln1g = (const float*)d_in[1];
    const float* ln1b = (const float*)d_in[2];
    // d_in[3..6] = Wq,bq,Wk,bk: dead code
    const float* Wv   = (const float*)d_in[7];
    const float* bv   = (const float*)d_in[8];
    const float* ln2g = (const float*)d_in[9];
    const float* ln2b = (const float*)d_in[10];
    const float* Wg   = (const float*)d_in[11];
    const float* bg   = (const float*)d_in[12];
    const float* W1   = (const float*)d_in[13];
    const float* b1   = (const float*)d_in[14];
    const float* W2   = (const float*)d_in[15];
    const float* b2   = (const float*)d_in[16];

    char* ws = (char*)d_ws;
    int*   cnt  = (int*)(ws + OFF_CNT);
    int*   buck = (int*)(ws + OFF_BUCK);
    u16*   h2   = (u16*)(ws + OFF_H2);
    u16*   hmid = (u16*)(ws + OFF_HMID);
    float* out  = (float*)d_out;

    hipMemsetAsync(cnt, 0, NE * sizeof(int), stream);
    k_front<<<T_TOK, 64, 0, stream>>>(x, ln1g, ln1b, Wv, bv, ln2g, ln2b,
                                      Wg, bg, b2, h2, out, cnt, buck);
    k_moe_gemm1<<<dim3(FF / 64, NE, 13), 256, 0, stream>>>(h2, W1, b1, cnt, buck, hmid);
    k_moe_gemm2<<<dim3(DM / 64, NE, 52), 256, 0, stream>>>(hmid, W2, cnt, buck, out);
}

// Round 4
// 276.635 us; speedup vs baseline: 1.0322x; 1.0322x over previous
//
#include <hip/hip_runtime.h>
#include <hip/hip_bf16.h>

// TransformerBlock: B=8,S=196,D=768,H=12,HD=64,E=8,FF=3072. T = B*S = 1568 tokens.
//
// Exact simplifications:
//  - attention: k,v broadcast across heads -> logits constant over softmax axis
//    -> softmax uniform -> attn_out = tile(v). Wq/bq/Wk/bk/RoPE are dead code.
//  - MoE top-1 = argmax of gating logits (softmax monotone).
//
// R5 structure:
//  - k_front: 1 wave/token. R4 post-mortem: vproj was 768 scalar dword loads
//    per lane -> L2-latency serialized (~1375 cy per 8-k step, VALUBusy 4.5%).
//    Now vproj loads Wv as f32x4 (wave = 4 contiguous rows = 1KB/instr):
//    group g=lane>>4 owns rows k%4==g, sublane sl=lane&15 owns cols 4sl..4sl+3;
//    192 loads/lane (4x fewer), unroll 8; h1 via LDS broadcast (conflict-free);
//    8 shfl_xor cross-group reduce lands v directly in the phase-C layout
//    (vsh LDS buffer + barrier deleted).
//  - MoE GEMMs unchanged: BM=128,BN=64,BK=64, depth-2 reg prefetch, raw
//    s_barrier (no vmcnt drain), clamped A-token indices.
//  - GEMM2 split-K x4 atomicAdds onto out pre-initialized with x2 + b2[expert].

typedef unsigned short u16;
typedef short bf16x8_t __attribute__((ext_vector_type(8)));
typedef unsigned short u16x4_t __attribute__((ext_vector_type(4)));
typedef float f32x4_t  __attribute__((ext_vector_type(4)));

#define T_TOK 1568
#define DM 768
#define HD 64
#define FF 3072
#define NE 8

// workspace layout (16B-aligned offsets; ~12.1 MB total)
#define OFF_CNT   0
#define OFF_BUCK  256
#define OFF_H2    (OFF_BUCK + NE*T_TOK*4)
#define OFF_HMID  (OFF_H2 + T_TOK*DM*2)

__device__ __forceinline__ u16 f2bf(float f) {  // RNE via HW cvt
    return __builtin_bit_cast(u16, __float2bfloat16(f));
}
__device__ __forceinline__ float gelu_f(float x) {
    return 0.5f * x * (1.0f + erff(x * 0.70710678118654752440f));
}

#define SFENCE() __builtin_amdgcn_sched_barrier(0)
#define RAW_BAR() __builtin_amdgcn_s_barrier()

// ---------------- K1: fused per-token front end (1 wave / token) ----------------
// Lane owns cols c(i,m) = 4*lane + 256*i + m (i<3, m<4): all param/x/out
// accesses are coalesced f32x4. vproj: f32x4 Wv loads, see header comment.
__global__ __launch_bounds__(64) void k_front(
        const float* __restrict__ x,
        const float* __restrict__ g1, const float* __restrict__ b1,
        const float* __restrict__ Wv, const float* __restrict__ bv,
        const float* __restrict__ g2, const float* __restrict__ b2g,
        const float* __restrict__ Wg, const float* __restrict__ bg,
        const float* __restrict__ b2moe,
        u16* __restrict__ h2, float* __restrict__ out,
        int* __restrict__ cnt, int* __restrict__ buck) {
    __shared__ __align__(16) float h1s[DM];   // 3 KB
    int t = blockIdx.x;
    int lane = threadIdx.x;                   // 0..63, single wave

    const float* xp = x + (size_t)t * DM;
    // ---- LN1 ----
    f32x4_t xv[3];
    float s = 0.0f;
#pragma unroll
    for (int i = 0; i < 3; i++) {
        xv[i] = *(const f32x4_t*)&xp[4 * lane + 256 * i];
        s += xv[i][0] + xv[i][1] + xv[i][2] + xv[i][3];
    }
#pragma unroll
    for (int m = 1; m < 64; m <<= 1) s += __shfl_xor(s, m);
    float mu = s * (1.0f / DM);
    float vs = 0.0f;
#pragma unroll
    for (int i = 0; i < 3; i++)
#pragma unroll
        for (int m = 0; m < 4; m++) { float d = xv[i][m] - mu; vs += d * d; }
#pragma unroll
    for (int m = 1; m < 64; m <<= 1) vs += __shfl_xor(vs, m);
    float rs = rsqrtf(vs * (1.0f / DM) + 1e-5f);
#pragma unroll
    for (int i = 0; i < 3; i++) {
        int c = 4 * lane + 256 * i;
        f32x4_t gg = *(const f32x4_t*)&g1[c];
        f32x4_t bb = *(const f32x4_t*)&b1[c];
        f32x4_t h;
#pragma unroll
        for (int m = 0; m < 4; m++) h[m] = (xv[i][m] - mu) * rs * gg[m] + bb[m];
        *(f32x4_t*)&h1s[c] = h;
    }
    __syncthreads();

    // ---- vproj: v[4*sl+m] = sum_k h1s[k] * Wv[k][4*sl+m] ----
    // group g rows k%4==g; wave-load = 4 contiguous rows of Wv = 1KB.
    int g = lane >> 4, sl = lane & 15;
    float a0 = 0.f, a1 = 0.f, a2 = 0.f, a3 = 0.f;
    {
        const float* wp = Wv + g * HD + 4 * sl;
#pragma unroll 8
        for (int kk = 0; kk < 192; kk++) {
            f32x4_t w4 = *(const f32x4_t*)&wp[(size_t)kk * (4 * HD)];
            float h = h1s[4 * kk + g];        // broadcast within 16-lane group
            a0 += h * w4[0]; a1 += h * w4[1]; a2 += h * w4[2]; a3 += h * w4[3];
        }
    }
    // cross-group reduce: lanes sl, sl+16, sl+32, sl+48 hold the same cols
    a0 += __shfl_xor(a0, 16); a0 += __shfl_xor(a0, 32);
    a1 += __shfl_xor(a1, 16); a1 += __shfl_xor(a1, 32);
    a2 += __shfl_xor(a2, 16); a2 += __shfl_xor(a2, 32);
    a3 += __shfl_xor(a3, 16); a3 += __shfl_xor(a3, 32);
    f32x4_t bvv = *(const f32x4_t*)&bv[4 * sl];
    f32x4_t vv = { a0 + bvv[0], a1 + bvv[1], a2 + bvv[2], a3 + bvv[3] };

    // ---- x2 = x + tile(v); LN2; gate; out init ----
    // col c = 4*lane + 256*i + m -> v[c & 63] = v[4*(lane&15) + m] = vv[m]
    float s2 = 0.0f;
#pragma unroll
    for (int i = 0; i < 3; i++)
#pragma unroll
        for (int m = 0; m < 4; m++) { xv[i][m] += vv[m]; s2 += xv[i][m]; }
#pragma unroll
    for (int m = 1; m < 64; m <<= 1) s2 += __shfl_xor(s2, m);
    float mu2 = s2 * (1.0f / DM);
    float vs2 = 0.0f;
#pragma unroll
    for (int i = 0; i < 3; i++)
#pragma unroll
        for (int m = 0; m < 4; m++) { float d = xv[i][m] - mu2; vs2 += d * d; }
#pragma unroll
    for (int m = 1; m < 64; m <<= 1) vs2 += __shfl_xor(vs2, m);
    float rs2 = rsqrtf(vs2 * (1.0f / DM) + 1e-5f);

    float le[NE];
#pragma unroll
    for (int e = 0; e < NE; e++) le[e] = 0.0f;
    u16* h2p = h2 + (size_t)t * DM;
#pragma unroll
    for (int i = 0; i < 3; i++) {
        int c = 4 * lane + 256 * i;
        f32x4_t gg = *(const f32x4_t*)&g2[c];
        f32x4_t bb = *(const f32x4_t*)&b2g[c];
        float h[4];
        u16x4_t hb;
#pragma unroll
        for (int m = 0; m < 4; m++) {
            h[m] = (xv[i][m] - mu2) * rs2 * gg[m] + bb[m];
            hb[m] = f2bf(h[m]);
        }
        *(u16x4_t*)&h2p[c] = hb;   // 8B coalesced
        // gate: rows c..c+3 of Wg[768][8] are 128B contiguous per lane
#pragma unroll
        for (int m = 0; m < 4; m++) {
            f32x4_t w0 = *(const f32x4_t*)&Wg[(size_t)(c + m) * NE];
            f32x4_t w1 = *(const f32x4_t*)&Wg[(size_t)(c + m) * NE + 4];
            le[0] += h[m] * w0[0]; le[1] += h[m] * w0[1];
            le[2] += h[m] * w0[2]; le[3] += h[m] * w0[3];
            le[4] += h[m] * w1[0]; le[5] += h[m] * w1[1];
            le[6] += h[m] * w1[2]; le[7] += h[m] * w1[3];
        }
    }
#pragma unroll
    for (int e = 0; e < NE; e++) {
#pragma unroll
        for (int m = 1; m < 64; m <<= 1) le[e] += __shfl_xor(le[e], m);
    }
    // all lanes hold bitwise-identical le[] (butterfly) -> uniform argmax
    float best = le[0] + bg[0]; int be = 0;
#pragma unroll
    for (int e = 1; e < NE; e++) {
        float q = le[e] + bg[e];
        if (q > best) { best = q; be = e; }   // strict > == first-max (jnp.argmax)
    }
    if (lane == 0) {
        int pos = atomicAdd(&cnt[be], 1);
        buck[be * T_TOK + pos] = t;
    }
    // out init: x2 + b2[be]  (gemm2 atomicAdds the MoE matmul on top)
    float* op = out + (size_t)t * DM;
    const float* bp = b2moe + (size_t)be * DM;
#pragma unroll
    for (int i = 0; i < 3; i++) {
        int c = 4 * lane + 256 * i;
        f32x4_t bbv = *(const f32x4_t*)&bp[c];
        f32x4_t o;
#pragma unroll
        for (int m = 0; m < 4; m++) o[m] = xv[i][m] + bbv[m];
        *(f32x4_t*)&op[c] = o;
    }
}

// ---------------- K2: grouped GEMM1 + gelu: hmid = gelu(h2 @ W1[e] + b1[e]) ----------------
// BM=128, BN=64, BK=64; 4 waves, wave -> 32-row strip x 64 cols.
// Depth-2 register prefetch + raw barriers (no vmcnt drain).
__global__ __launch_bounds__(256, 3) void k_moe_gemm1(
        const u16* __restrict__ h2, const float* __restrict__ W1,
        const float* __restrict__ b1, const int* __restrict__ cnt,
        const int* __restrict__ buck, u16* __restrict__ hmid) {
    int nt = blockIdx.x, e = blockIdx.y, mt = blockIdx.z;
    int cnte = cnt[e];
    int m0 = mt * 128;
    if (m0 >= cnte) return;
    int n0 = nt * 64;
    const float* W1e = W1 + (size_t)e * DM * FF;
    __shared__ __align__(16) u16 As[128 * 72];   // 18 KB
    __shared__ __align__(16) u16 Bs[64 * 72];    // 9 KB, [n][k]
    int tid = threadIdx.x, lane = tid & 63, wid = tid >> 6;

    // A staging: row = tid>>3 (+32j), col-chunk = tid&7. Clamped (unconditional).
    int arow = tid >> 3, ac = tid & 7;
    int atok[4];
#pragma unroll
    for (int j = 0; j < 4; j++) {
        int i = m0 + arow + 32 * j;
        if (i >= cnte) i = cnte - 1;           // garbage rows, never stored
        atok[j] = buck[e * T_TOK + i];
    }
    int bn = tid & 63, bkg = tid >> 6;

    f32x4_t acc[2][4];
#pragma unroll
    for (int mi = 0; mi < 2; mi++)
#pragma unroll
        for (int ni = 0; ni < 4; ni++) acc[mi][ni] = (f32x4_t){0.f, 0.f, 0.f, 0.f};

    bf16x8_t aP[4], aQ[4];
    float bP[16], bQ[16];

#define G_LOAD(SA, SB, KT) { \
    int k0_ = (KT) * 64; \
    _Pragma("unroll") \
    for (int j = 0; j < 4; j++) \
        SA[j] = *(const bf16x8_t*)&h2[(size_t)atok[j] * DM + k0_ + ac * 8]; \
    const float* bp_ = W1e + (size_t)(k0_ + bkg * 16) * FF + n0 + bn; \
    _Pragma("unroll") \
    for (int kk = 0; kk < 16; kk++) SB[kk] = bp_[(size_t)kk * FF]; \
}
#define STORE_LDS(SA, SB) { \
    _Pragma("unroll") \
    for (int j = 0; j < 4; j++) \
        *(bf16x8_t*)&As[(arow + 32 * j) * 72 + ac * 8] = SA[j]; \
    bf16x8_t p0_, p1_; \
    _Pragma("unroll") \
    for (int kk = 0; kk < 8; kk++) { \
        p0_[kk] = (short)f2bf(SB[kk]); \
        p1_[kk] = (short)f2bf(SB[kk + 8]); \
    } \
    *(bf16x8_t*)&Bs[bn * 72 + bkg * 16] = p0_; \
    *(bf16x8_t*)&Bs[bn * 72 + bkg * 16 + 8] = p1_; \
}
#define MFMA_TILE() { \
    int lr_ = lane & 15, q_ = lane >> 4; \
    _Pragma("unroll") \
    for (int s = 0; s < 2; s++) { \
        bf16x8_t af[2], bfr[4]; \
        _Pragma("unroll") \
        for (int mi = 0; mi < 2; mi++) \
            af[mi] = *(const bf16x8_t*)&As[(wid * 32 + mi * 16 + lr_) * 72 + s * 32 + q_ * 8]; \
        _Pragma("unroll") \
        for (int ni = 0; ni < 4; ni++) \
            bfr[ni] = *(const bf16x8_t*)&Bs[(ni * 16 + lr_) * 72 + s * 32 + q_ * 8]; \
        _Pragma("unroll") \
        for (int mi = 0; mi < 2; mi++) \
            _Pragma("unroll") \
            for (int ni = 0; ni < 4; ni++) \
                acc[mi][ni] = __builtin_amdgcn_mfma_f32_16x16x32_bf16( \
                    af[mi], bfr[ni], acc[mi][ni], 0, 0, 0); \
    } \
}
// one k-tile phase: raw barriers; own-wave lgkmcnt(0) after stores; prefetch
// set stays in flight across barriers (compiler emits counted vmcnt for the
// reg->LDS dependency only).
#define PHASE(SA, SB, PKT) { \
    SFENCE(); RAW_BAR(); SFENCE(); \
    STORE_LDS(SA, SB) \
    asm volatile("s_waitcnt lgkmcnt(0)" ::: "memory"); \
    SFENCE(); RAW_BAR(); SFENCE(); \
    if ((PKT) < 12) G_LOAD(SA, SB, PKT) \
    MFMA_TILE() \
}

    G_LOAD(aP, bP, 0)
    G_LOAD(aQ, bQ, 1)
    for (int kt = 0; kt < 12; kt += 2) {
        PHASE(aP, bP, kt + 2)
        PHASE(aQ, bQ, kt + 3)
    }
#undef G_LOAD
#undef STORE_LDS
#undef MFMA_TILE
#undef PHASE

    // epilogue: bias + gelu, scatter by token id
    int lr = lane & 15, q = lane >> 4;
    float bias[4];
#pragma unroll
    for (int ni = 0; ni < 4; ni++) bias[ni] = b1[(size_t)e * FF + n0 + ni * 16 + lr];
#pragma unroll
    for (int mi = 0; mi < 2; mi++) {
#pragma unroll
        for (int r = 0; r < 4; r++) {
            int i = m0 + wid * 32 + mi * 16 + q * 4 + r;
            if (i < cnte) {
                int t = buck[e * T_TOK + i];
                size_t base = (size_t)t * FF + n0;
#pragma unroll
                for (int ni = 0; ni < 4; ni++) {
                    float vv = acc[mi][ni][r] + bias[ni];
                    hmid[base + ni * 16 + lr] = f2bf(gelu_f(vv));
                }
            }
        }
    }
}

// ---------------- K3: grouped GEMM2 split-K x4: out += hmid @ W2[e] ----------------
// BM=128, BN=64, BK=64, K-chunk = FF/4 = 768. z = mt*4 + kc. Depth-2 prefetch,
// raw barriers.
__global__ __launch_bounds__(256, 3) void k_moe_gemm2(
        const u16* __restrict__ hmid, const float* __restrict__ W2,
        const int* __restrict__ cnt, const int* __restrict__ buck,
        float* __restrict__ out) {
    int nt = blockIdx.x, e = blockIdx.y, z = blockIdx.z;
    int kc = z & 3, mt = z >> 2;
    int cnte = cnt[e];
    int m0 = mt * 128;
    if (m0 >= cnte) return;
    int n0 = nt * 64;
    int kbase = kc * (FF / 4);
    const float* W2e = W2 + (size_t)e * FF * DM;
    __shared__ __align__(16) u16 As[128 * 72];
    __shared__ __align__(16) u16 Bs[64 * 72];
    int tid = threadIdx.x, lane = tid & 63, wid = tid >> 6;

    int arow = tid >> 3, ac = tid & 7;
    int atok[4];
#pragma unroll
    for (int j = 0; j < 4; j++) {
        int i = m0 + arow + 32 * j;
        if (i >= cnte) i = cnte - 1;           // garbage rows, never stored
        atok[j] = buck[e * T_TOK + i];
    }
    int bn = tid & 63, bkg = tid >> 6;

    f32x4_t acc[2][4];
#pragma unroll
    for (int mi = 0; mi < 2; mi++)
#pragma unroll
        for (int ni = 0; ni < 4; ni++) acc[mi][ni] = (f32x4_t){0.f, 0.f, 0.f, 0.f};

    bf16x8_t aP[4], aQ[4];
    float bP[16], bQ[16];

#define G_LOAD(SA, SB, KT) { \
    int k0_ = kbase + (KT) * 64; \
    _Pragma("unroll") \
    for (int j = 0; j < 4; j++) \
        SA[j] = *(const bf16x8_t*)&hmid[(size_t)atok[j] * FF + k0_ + ac * 8]; \
    const float* bp_ = W2e + (size_t)(k0_ + bkg * 16) * DM + n0 + bn; \
    _Pragma("unroll") \
    for (int kk = 0; kk < 16; kk++) SB[kk] = bp_[(size_t)kk * DM]; \
}
#define STORE_LDS(SA, SB) { \
    _Pragma("unroll") \
    for (int j = 0; j < 4; j++) \
        *(bf16x8_t*)&As[(arow + 32 * j) * 72 + ac * 8] = SA[j]; \
    bf16x8_t p0_, p1_; \
    _Pragma("unroll") \
    for (int kk = 0; kk < 8; kk++) { \
        p0_[kk] = (short)f2bf(SB[kk]); \
        p1_[kk] = (short)f2bf(SB[kk + 8]); \
    } \
    *(bf16x8_t*)&Bs[bn * 72 + bkg * 16] = p0_; \
    *(bf16x8_t*)&Bs[bn * 72 + bkg * 16 + 8] = p1_; \
}
#define MFMA_TILE() { \
    int lr_ = lane & 15, q_ = lane >> 4; \
    _Pragma("unroll") \
    for (int s = 0; s < 2; s++) { \
        bf16x8_t af[2], bfr[4]; \
        _Pragma("unroll") \
        for (int mi = 0; mi < 2; mi++) \
            af[mi] = *(const bf16x8_t*)&As[(wid * 32 + mi * 16 + lr_) * 72 + s * 32 + q_ * 8]; \
        _Pragma("unroll") \
        for (int ni = 0; ni < 4; ni++) \
            bfr[ni] = *(const bf16x8_t*)&Bs[(ni * 16 + lr_) * 72 + s * 32 + q_ * 8]; \
        _Pragma("unroll") \
        for (int mi = 0; mi < 2; mi++) \
            _Pragma("unroll") \
            for (int ni = 0; ni < 4; ni++) \
                acc[mi][ni] = __builtin_amdgcn_mfma_f32_16x16x32_bf16( \
                    af[mi], bfr[ni], acc[mi][ni], 0, 0, 0); \
    } \
}
#define PHASE(SA, SB, PKT) { \
    SFENCE(); RAW_BAR(); SFENCE(); \
    STORE_LDS(SA, SB) \
    asm volatile("s_waitcnt lgkmcnt(0)" ::: "memory"); \
    SFENCE(); RAW_BAR(); SFENCE(); \
    if ((PKT) < 12) G_LOAD(SA, SB, PKT) \
    MFMA_TILE() \
}

    G_LOAD(aP, bP, 0)
    G_LOAD(aQ, bQ, 1)
    for (int kt = 0; kt < 12; kt += 2) {
        PHASE(aP, bP, kt + 2)
        PHASE(aQ, bQ, kt + 3)
    }
#undef G_LOAD
#undef STORE_LDS
#undef MFMA_TILE
#undef PHASE

    // epilogue: atomicAdd partials into out (out pre-initialized with x2 + b2[e])
    int lr = lane & 15, q = lane >> 4;
#pragma unroll
    for (int mi = 0; mi < 2; mi++) {
#pragma unroll
        for (int r = 0; r < 4; r++) {
            int i = m0 + wid * 32 + mi * 16 + q * 4 + r;
            if (i < cnte) {
                int t = buck[e * T_TOK + i];
                size_t base = (size_t)t * DM + n0;
#pragma unroll
                for (int ni = 0; ni < 4; ni++)
                    atomicAdd(&out[base + ni * 16 + lr], acc[mi][ni][r]);
            }
        }
    }
}

extern "C" void kernel_launch(void* const* d_in, const int* in_sizes, int n_in,
                              void* d_out, int out_size, void* d_ws, size_t ws_size,
                              hipStream_t stream) {
    const float* x    = (const float*)d_in[0];
    const float* ln1g = (const float*)d_in[1];
    const float* ln1b = (const float*)d_in[2];
    // d_in[3..6] = Wq,bq,Wk,bk: dead code
    const float* Wv   = (const float*)d_in[7];
    const float* bv   = (const float*)d_in[8];
    const float* ln2g = (const float*)d_in[9];
    const float* ln2b = (const float*)d_in[10];
    const float* Wg   = (const float*)d_in[11];
    const float* bg   = (const float*)d_in[12];
    const float* W1   = (const float*)d_in[13];
    const float* b1   = (const float*)d_in[14];
    const float* W2   = (const float*)d_in[15];
    const float* b2   = (const float*)d_in[16];

    char* ws = (char*)d_ws;
    int*   cnt  = (int*)(ws + OFF_CNT);
    int*   buck = (int*)(ws + OFF_BUCK);
    u16*   h2   = (u16*)(ws + OFF_H2);
    u16*   hmid = (u16*)(ws + OFF_HMID);
    float* out  = (float*)d_out;

    hipMemsetAsync(cnt, 0, NE * sizeof(int), stream);
    k_front<<<T_TOK, 64, 0, stream>>>(x, ln1g, ln1b, Wv, bv, ln2g, ln2b,
                                      Wg, bg, b2, h2, out, cnt, buck);
    k_moe_gemm1<<<dim3(FF / 64, NE, 13), 256, 0, stream>>>(h2, W1, b1, cnt, buck, hmid);
    k_moe_gemm2<<<dim3(DM / 64, NE, 52), 256, 0, stream>>>(hmid, W2, cnt, buck, out);
}